// Round 8
// baseline (802.500 us; speedup 1.0000x reference)
//
#include <hip/hip_runtime.h>
#include <hip/hip_bf16.h>

#define BB 8192
#define TT 64
#define L2E 1.44269504088896f
#define PGROW 516   // partial-gate row stride (shorts); 1032 B -> rows step 2 banks
#define LSTM_LDS_BYTES (8192 + 8192 + 2*32*PGROW*2 + 16384)  // es + hs + pg[2] + xs = 98816

typedef __attribute__((ext_vector_type(8))) short bf16x8;
typedef __attribute__((ext_vector_type(4))) short bf16x4;
typedef __attribute__((ext_vector_type(4))) float f32x4;

__device__ __forceinline__ float exp2g(float x) { return __builtin_amdgcn_exp2f(x); }
__device__ __forceinline__ float rcpg(float x)  { return __builtin_amdgcn_rcpf(x); }
__device__ __forceinline__ short f2bf_s(float x) {
  __hip_bfloat16 b = __float2bfloat16(x);
  return *reinterpret_cast<short*>(&b);
}
__device__ __forceinline__ float bf2f(short v) {
  unsigned u = ((unsigned)(unsigned short)v) << 16;
  return __uint_as_float(u);
}
// [32][128]-short tile, 16B-granule XOR swizzle
__device__ __forceinline__ bf16x8 ldfrag128(const short* base, int row, int kg) {
  return *(const bf16x8*)&base[row * 128 + ((kg ^ (row & 7)) << 3)];
}

// ---- 1. weights -> bf16 A-operand fragments (gate-packed cols, exp2-prescaled);
//         bcg[j*4+gate] = scaled combined bias ----
__global__ void prep_kernel(const float* __restrict__ Wih, const float* __restrict__ Whh,
                            const float* __restrict__ bih, const float* __restrict__ bhh,
                            const float* __restrict__ Wout,
                            short* __restrict__ Wcb, short* __restrict__ Woutb,
                            float* __restrict__ bcg) {
  int idx = blockIdx.x * 256 + threadIdx.x;   // 17152 total
  if (idx < 16384) {
    int l = idx & 63, f = idx >> 6;
    int mt = f >> 3, kt = f & 7;
    int mloc = l & 15;
    int j = mt * 4 + (mloc >> 2);
    int gate = mloc & 3;
    int c = gate * 128 + j;
    int k0 = kt * 32 + ((l >> 4) << 3);
    float s = (gate == 2) ? (2.f * L2E) : (-L2E);
    const float* src = (k0 < 128) ? (Wih + c * 128 + k0) : (Whh + c * 128 + (k0 - 128));
    bf16x8 v;
    #pragma unroll
    for (int e = 0; e < 8; e++) v[e] = f2bf_s(src[e] * s);
    *(bf16x8*)(Wcb + (size_t)idx * 8) = v;
  } else if (idx < 16640) {
    int i2 = idx - 16384;
    int l = i2 & 63, f = i2 >> 6;              // f = kyt
    int k0 = f * 32 + ((l >> 4) << 3);
    int col = l & 15;
    bf16x8 v;
    #pragma unroll
    for (int e = 0; e < 8; e++)
      v[e] = (col < 5) ? f2bf_s(Wout[col * 128 + k0 + e]) : (short)0;
    *(bf16x8*)(Woutb + (size_t)i2 * 8) = v;
  } else {
    int i3 = idx - 16640;                      // gate*128 + j
    int gate = i3 >> 7, j = i3 & 127;
    float s = (gate == 2) ? (2.f * L2E) : (-L2E);
    bcg[j * 4 + gate] = (bih[i3] + bhh[i3]) * s;
  }
}

// ---- 2. per-t raw input moments over batch ----
__global__ void stats_kernel(const float* __restrict__ x, float* __restrict__ stats) {
  int t = blockIdx.x, tid = threadIdx.x;
  float s0=0, s1=0, s2=0, s3=0, s4=0;
  for (int b = tid; b < BB; b += 256) {
    const float* p = x + ((size_t)b * TT + t) * 2;
    float x0 = p[0], x1 = p[1];
    s0 += x0; s1 += x1; s2 += x0*x0; s3 += x0*x1; s4 += x1*x1;
  }
  __shared__ float red[4][5];
  int lane = tid & 63, w = tid >> 6;
  #pragma unroll
  for (int off = 32; off > 0; off >>= 1) {
    s0 += __shfl_down(s0, off); s1 += __shfl_down(s1, off);
    s2 += __shfl_down(s2, off); s3 += __shfl_down(s3, off); s4 += __shfl_down(s4, off);
  }
  if (lane == 0) { red[w][0]=s0; red[w][1]=s1; red[w][2]=s2; red[w][3]=s3; red[w][4]=s4; }
  __syncthreads();
  if (tid < 5) stats[t*5 + tid] = red[0][tid] + red[1][tid] + red[2][tid] + red[3][tid];
}

// ---- 3. fold input-BN + embed Linear + per-step embed-BN into A0/A1/C ----
__global__ void coef_kernel(const float* __restrict__ stats,
                            const float* __restrict__ Wemb, const float* __restrict__ bemb,
                            const float* __restrict__ ing, const float* __restrict__ inb,
                            const float* __restrict__ eg, const float* __restrict__ eb,
                            float* __restrict__ A0, float* __restrict__ A1, float* __restrict__ Ct) {
  __shared__ float st[64][5];
  __shared__ float glob[4];
  int tid = threadIdx.x;  // 128
  for (int i = tid; i < 320; i += 128) st[i / 5][i % 5] = stats[i];
  __syncthreads();
  if (tid == 0) {
    float S0=0, S1=0, S00=0, S11=0;
    for (int t = 0; t < 64; t++) { S0+=st[t][0]; S1+=st[t][1]; S00+=st[t][2]; S11+=st[t][4]; }
    float inv_n = 1.f / (float)(BB * TT);
    float M0 = S0*inv_n, M1 = S1*inv_n;
    float V0 = S00*inv_n - M0*M0, V1 = S11*inv_n - M1*M1;
    float P0 = rsqrtf(V0 + 1e-5f) * ing[0];
    float P1 = rsqrtf(V1 + 1e-5f) * ing[1];
    glob[0]=P0; glob[1]=P1; glob[2]=inb[0]-M0*P0; glob[3]=inb[1]-M1*P1;
  }
  __syncthreads();
  float P0=glob[0], P1=glob[1], Q0=glob[2], Q1=glob[3];
  int j = tid;
  float w0 = Wemb[j*2], w1 = Wemb[j*2+1];
  float a0 = P0*w0, a1 = P1*w1;
  float cj = Q0*w0 + Q1*w1 + bemb[j];
  float gam = eg[j], bet = eb[j];
  float invB = 1.f / (float)BB;
  for (int t = 0; t < 64; t++) {
    float m0 = st[t][0]*invB, m1 = st[t][1]*invB;
    float v00 = st[t][2]*invB - m0*m0;
    float v01 = st[t][3]*invB - m0*m1;
    float v11 = st[t][4]*invB - m1*m1;
    float mean = a0*m0 + a1*m1 + cj;
    float var  = a0*a0*v00 + 2.f*a0*a1*v01 + a1*a1*v11;
    float G = rsqrtf(var + 1e-5f) * gam;
    A0[t*128 + j] = G * a0;
    A1[t*128 + j] = G * a1;
    Ct[t*128 + j] = G * cj + (bet - mean * G);
  }
}

// write e(t): e-threads (tid<512), er = tid>>4, cg = tid&15 (8 cols each)
__device__ __forceinline__ void write_e(short* es,
                                        const float* __restrict__ A0, const float* __restrict__ A1,
                                        const float* __restrict__ Ct,
                                        int t, int er, int cg, const float* __restrict__ xs) {
  const float* a0p = A0 + t*128 + cg*8;
  const float* a1p = A1 + t*128 + cg*8;
  const float* ccp = Ct + t*128 + cg*8;
  const float4 a0a = *(const float4*)a0p, a0b = *(const float4*)(a0p + 4);
  const float4 a1a = *(const float4*)a1p, a1b = *(const float4*)(a1p + 4);
  const float4 cta = *(const float4*)ccp, ctb = *(const float4*)(ccp + 4);
  float x0 = xs[er * 128 + t * 2], x1 = xs[er * 128 + t * 2 + 1];
  bf16x8 v;
  v[0] = f2bf_s(fmaxf(fmaf(a0a.x, x0, fmaf(a1a.x, x1, cta.x)), 0.f));
  v[1] = f2bf_s(fmaxf(fmaf(a0a.y, x0, fmaf(a1a.y, x1, cta.y)), 0.f));
  v[2] = f2bf_s(fmaxf(fmaf(a0a.z, x0, fmaf(a1a.z, x1, cta.z)), 0.f));
  v[3] = f2bf_s(fmaxf(fmaf(a0a.w, x0, fmaf(a1a.w, x1, cta.w)), 0.f));
  v[4] = f2bf_s(fmaxf(fmaf(a0b.x, x0, fmaf(a1b.x, x1, ctb.x)), 0.f));
  v[5] = f2bf_s(fmaxf(fmaf(a0b.y, x0, fmaf(a1b.y, x1, ctb.y)), 0.f));
  v[6] = f2bf_s(fmaxf(fmaf(a0b.z, x0, fmaf(a1b.z, x1, ctb.z)), 0.f));
  v[7] = f2bf_s(fmaxf(fmaf(a0b.w, x0, fmaf(a1b.w, x1, ctb.w)), 0.f));
  *(bf16x8*)&es[er * 128 + ((cg ^ (er & 7)) << 3)] = v;
}

// ---- 4. split-K producer/consumer MFMA recurrence: 256 blocks x 32 rows, 16 waves ----
// waves 0-7 (e): write_e + y-proj (P1), e-part GEMM(t+1)->pg (P2)
// waves 8-15 (h): h-part GEMM(t) (P1), combine+activations+h-write (P2)
__launch_bounds__(1024, 1)
__global__ void lstm_kernel(const float* __restrict__ x,
                            const float* __restrict__ A0, const float* __restrict__ A1,
                            const float* __restrict__ Ctab,
                            const short* __restrict__ Wcb, const float* __restrict__ bcg,
                            const short* __restrict__ Woutb, const float* __restrict__ bout,
                            float* __restrict__ outy, float* __restrict__ hout,
                            float* __restrict__ cout) {
  extern __shared__ __align__(16) char smraw[];
  short* es = (short*)smraw;                         // [32][128] e(t)
  short* hs = (short*)(smraw + 8192);                // [32][128] h(t-1)
  short* pg = (short*)(smraw + 16384);               // [2][32][PGROW] bf16 partial gates
  float* xs = (float*)(smraw + 16384 + 2*32*PGROW*2);// [32][128]

  const int tid  = threadIdx.x;
  const int lane = tid & 63;
  const int w    = tid >> 6;      // 0..15
  const int eh   = w >> 3;        // 0 = e-half, 1 = h-half
  const int s8   = w & 7;         // M-group: M-tiles s8*4 .. s8*4+3
  const int cl   = lane & 15;     // batch row within N-tile
  const int lq   = lane >> 4;
  const int row0 = blockIdx.x * 32;
  const int er   = (tid >> 4) & 31;  // e-writer row
  const int cg   = tid & 15;         // e-writer granule

  // preload x (1024 float4 = 4096 floats = 32 rows x 128)
  ((float4*)xs)[tid] = ((const float4*)(x + (size_t)row0 * 128))[tid];

  // resident weights: this half's K-range, 16 frags = 64 VGPR
  bf16x8 wreg[4][4];  // [kt][mt]
  {
    const bf16x8* wptr = (const bf16x8*)Wcb;
    #pragma unroll
    for (int kt = 0; kt < 4; kt++)
      #pragma unroll
      for (int mt = 0; mt < 4; mt++)
        wreg[kt][mt] = wptr[(size_t)((s8 * 4 + mt) * 8 + eh * 4 + kt) * 64 + lane];
  }
  const float bov = (cl < 5) ? bout[cl] : 0.f;

  __syncthreads();  // xs ready

  // prologue: e(0) -> es (e-waves); hs = 0 (h-waves)
  if (!eh) {
    write_e(es, A0, A1, Ctab, 0, er, cg, xs);
  } else {
    int t2 = tid - 512;
    int zr = t2 >> 4, zg = t2 & 15;
    bf16x8 z = (bf16x8)0;
    *(bf16x8*)&hs[zr * 128 + ((zg ^ (zr & 7)) << 3)] = z;
  }
  __syncthreads();

  // prologue: e-part GEMM(0) -> pg[0]
  if (!eh) {
    #pragma unroll
    for (int nt = 0; nt < 2; nt++) {
      bf16x8 b[4];
      #pragma unroll
      for (int kt = 0; kt < 4; kt++) b[kt] = ldfrag128(es, nt * 16 + cl, kt * 4 + lq);
      #pragma unroll
      for (int mt = 0; mt < 4; mt++) {
        f32x4 ae = *(const f32x4*)&bcg[((s8 * 4 + mt) * 4 + lq) * 4];
        #pragma unroll
        for (int kt = 0; kt < 4; kt++)
          ae = __builtin_amdgcn_mfma_f32_16x16x32_bf16(wreg[kt][mt], b[kt], ae, 0, 0, 0);
        bf16x4 v;
        #pragma unroll
        for (int q = 0; q < 4; q++) v[q] = f2bf_s(ae[q]);
        *(bf16x4*)&pg[(nt * 16 + cl) * PGROW + (s8 * 4 + mt) * 16 + lq * 4] = v;
      }
    }
  }
  __syncthreads();  // pg[0] + es stable before P1(0) overwrites es

  f32x4 acc[4][2];
  float cst[4][2] = {{0,0},{0,0},{0,0},{0,0}};

  #pragma unroll 1
  for (int t = 0; t < TT; t++) {
    // ---------------- P1 ----------------
    if (eh) {
      // h-part GEMM(t): reads h(t-1) from hs
      #pragma unroll
      for (int mt = 0; mt < 4; mt++)
        #pragma unroll
        for (int nt = 0; nt < 2; nt++) acc[mt][nt] = (f32x4){0.f, 0.f, 0.f, 0.f};
      __builtin_amdgcn_s_setprio(1);
      #pragma unroll
      for (int nt = 0; nt < 2; nt++) {
        bf16x8 b[4];
        #pragma unroll
        for (int kt = 0; kt < 4; kt++) b[kt] = ldfrag128(hs, nt * 16 + cl, kt * 4 + lq);
        #pragma unroll
        for (int kt = 0; kt < 4; kt++)
          #pragma unroll
          for (int mt = 0; mt < 4; mt++)
            acc[mt][nt] = __builtin_amdgcn_mfma_f32_16x16x32_bf16(wreg[kt][mt], b[kt], acc[mt][nt], 0, 0, 0);
      }
      __builtin_amdgcn_s_setprio(0);
    } else {
      if (t < TT - 1) write_e(es, A0, A1, Ctab, t + 1, er, cg, xs);
      if (w < 2 && t > 0) {   // y(t-1) = h(t-1) @ Wout^T
        f32x4 ya = (f32x4){0.f, 0.f, 0.f, 0.f};
        #pragma unroll
        for (int kyt = 0; kyt < 4; kyt++) {
          bf16x8 wo = *(const bf16x8*)(Woutb + (size_t)(kyt * 64 + lane) * 8);
          bf16x8 ah = ldfrag128(hs, w * 16 + cl, kyt * 4 + lq);
          ya = __builtin_amdgcn_mfma_f32_16x16x32_bf16(ah, wo, ya, 0, 0, 0);
        }
        if (cl < 5) {
          #pragma unroll
          for (int q = 0; q < 4; q++)
            outy[((size_t)(row0 + w * 16 + lq * 4 + q) * TT + (t - 1)) * 5 + cl] = ya[q] + bov;
        }
      }
    }
    __syncthreads();  // barrier1: e(t+1) visible; h-GEMM reads of hs done

    // ---------------- P2 ----------------
    if (!eh) {
      if (t < TT - 1) {   // e-part GEMM(t+1) -> pg[(t+1)&1]
        short* pgd = pg + ((t + 1) & 1) * 32 * PGROW;
        __builtin_amdgcn_s_setprio(1);
        #pragma unroll
        for (int nt = 0; nt < 2; nt++) {
          bf16x8 b[4];
          #pragma unroll
          for (int kt = 0; kt < 4; kt++) b[kt] = ldfrag128(es, nt * 16 + cl, kt * 4 + lq);
          #pragma unroll
          for (int mt = 0; mt < 4; mt++) {
            f32x4 ae = *(const f32x4*)&bcg[((s8 * 4 + mt) * 4 + lq) * 4];
            #pragma unroll
            for (int kt = 0; kt < 4; kt++)
              ae = __builtin_amdgcn_mfma_f32_16x16x32_bf16(wreg[kt][mt], b[kt], ae, 0, 0, 0);
            bf16x4 v;
            #pragma unroll
            for (int q = 0; q < 4; q++) v[q] = f2bf_s(ae[q]);
            *(bf16x4*)&pgd[(nt * 16 + cl) * PGROW + (s8 * 4 + mt) * 16 + lq * 4] = v;
          }
        }
        __builtin_amdgcn_s_setprio(0);
      }
    } else {
      // combine + activations -> h(t)
      const short* pgs = pg + (t & 1) * 32 * PGROW;
      #pragma unroll
      for (int nt = 0; nt < 2; nt++) {
        #pragma unroll
        for (int mt = 0; mt < 4; mt++) {
          int row = nt * 16 + cl;
          int jj  = (s8 * 4 + mt) * 4 + lq;
          bf16x4 pv = *(const bf16x4*)&pgs[row * PGROW + (s8 * 4 + mt) * 16 + lq * 4];
          float Ei = exp2g(acc[mt][nt][0] + bf2f(pv[0]));   // e^{-i}
          float Ef = exp2g(acc[mt][nt][1] + bf2f(pv[1]));   // e^{-f}
          float Eg = exp2g(acc[mt][nt][2] + bf2f(pv[2]));   // e^{2g}
          float Eo = exp2g(acc[mt][nt][3] + bf2f(pv[3]));   // e^{-o}
          float ig = (Eg - 1.f) * rcpg((1.f + Ei) * (1.f + Eg));
          float fv = rcpg(1.f + Ef);
          float cn = fmaf(fv, cst[mt][nt], ig);
          cst[mt][nt] = cn;
          float Ec = exp2g(cn * (2.f * L2E));
          float hn = (Ec - 1.f) * rcpg((1.f + Eo) * (1.f + Ec));
          int g = jj >> 3;
          hs[row * 128 + ((g ^ (row & 7)) << 3) + (jj & 7)] = f2bf_s(hn);
          if (t == TT - 1) {
            hout[(size_t)(row0 + row) * 128 + jj] = hn;
            cout[(size_t)(row0 + row) * 128 + jj] = cn;
          }
        }
      }
    }
    __syncthreads();  // barrier2: h(t), pg(t+1) visible
  }

  // epilogue: y(63)
  if (w < 2) {
    f32x4 ya = (f32x4){0.f, 0.f, 0.f, 0.f};
    #pragma unroll
    for (int kyt = 0; kyt < 4; kyt++) {
      bf16x8 wo = *(const bf16x8*)(Woutb + (size_t)(kyt * 64 + lane) * 8);
      bf16x8 ah = ldfrag128(hs, w * 16 + cl, kyt * 4 + lq);
      ya = __builtin_amdgcn_mfma_f32_16x16x32_bf16(ah, wo, ya, 0, 0, 0);
    }
    if (cl < 5) {
      #pragma unroll
      for (int q = 0; q < 4; q++)
        outy[((size_t)(row0 + w * 16 + lq * 4 + q) * TT + (TT - 1)) * 5 + cl] = ya[q] + bov;
    }
  }
}

// ---- 5. per-(t,k) output BN partial stats (256 blocks = full chip) ----
__global__ void ostats_kernel(const float* __restrict__ outy, float* __restrict__ ostp) {
  int t = blockIdx.x >> 2, part = blockIdx.x & 3;
  int tid = threadIdx.x;
  float s[5] = {0,0,0,0,0}, s2[5] = {0,0,0,0,0};
  int b0 = part * 2048;
  for (int b = b0 + tid; b < b0 + 2048; b += 256) {
    const float* p = outy + ((size_t)b * TT + t) * 5;
    #pragma unroll
    for (int k = 0; k < 5; k++) { float v = p[k]; s[k] += v; s2[k] += v*v; }
  }
  __shared__ float red[4][10];
  int lane = tid & 63, w = tid >> 6;
  #pragma unroll
  for (int off = 32; off > 0; off >>= 1) {
    #pragma unroll
    for (int k = 0; k < 5; k++) {
      s[k]  += __shfl_down(s[k], off);
      s2[k] += __shfl_down(s2[k], off);
    }
  }
  if (lane == 0) {
    #pragma unroll
    for (int k = 0; k < 5; k++) { red[w][k] = s[k]; red[w][5+k] = s2[k]; }
  }
  __syncthreads();
  if (tid < 10) ostp[blockIdx.x * 10 + tid] = red[0][tid]+red[1][tid]+red[2][tid]+red[3][tid];
}

// ---- 5b. finalize: per-(t,k) scale/shift ----
__global__ void ofin_kernel(const float* __restrict__ ostp,
                            const float* __restrict__ og, const float* __restrict__ ob,
                            float* __restrict__ sc, float* __restrict__ sh) {
  int i = threadIdx.x;               // 320
  if (i >= 320) return;
  int t = i / 5, k = i - t * 5;
  const float invB = 1.f / (float)BB;
  float m  = (ostp[(t*4+0)*10+k]   + ostp[(t*4+1)*10+k]   + ostp[(t*4+2)*10+k]   + ostp[(t*4+3)*10+k]) * invB;
  float s2 = (ostp[(t*4+0)*10+5+k] + ostp[(t*4+1)*10+5+k] + ostp[(t*4+2)*10+5+k] + ostp[(t*4+3)*10+5+k]) * invB;
  float v = s2 - m * m;
  float scale = rsqrtf(v + 1e-5f) * og[k];
  sc[i] = scale;
  sh[i] = ob[k] - m * scale;
}

// ---- 6. normalize outs in place ----
__global__ void onorm_kernel(float* __restrict__ outy, const float* __restrict__ sc,
                             const float* __restrict__ sh) {
  const int N = BB * TT * 5;
  for (int i = blockIdx.x * 256 + threadIdx.x; i < N; i += gridDim.x * 256) {
    int j = i % 320;
    outy[i] = fmaf(outy[i], sc[j], sh[j]);
  }
}

extern "C" void kernel_launch(void* const* d_in, const int* in_sizes, int n_in,
                              void* d_out, int out_size, void* d_ws, size_t ws_size,
                              hipStream_t stream) {
  const float* xin  = (const float*)d_in[0];
  const float* ing  = (const float*)d_in[1];
  const float* inb  = (const float*)d_in[2];
  const float* Wemb = (const float*)d_in[3];
  const float* bemb = (const float*)d_in[4];
  const float* eg   = (const float*)d_in[5];
  const float* eb   = (const float*)d_in[6];
  const float* Wih  = (const float*)d_in[7];
  const float* Whh  = (const float*)d_in[8];
  const float* bih  = (const float*)d_in[9];
  const float* bhh  = (const float*)d_in[10];
  const float* Wout = (const float*)d_in[11];
  const float* bout = (const float*)d_in[12];
  const float* og   = (const float*)d_in[13];
  const float* ob   = (const float*)d_in[14];

  float* ws    = (float*)d_ws;
  float* stats = ws;             // 320
  float* A0    = ws + 1024;      // 8192
  float* A1    = ws + 9216;      // 8192
  float* Ct    = ws + 17408;     // 8192
  float* bcg   = ws + 25600;     // 512
  short* Wcb   = (short*)(ws + 26624);   // 131072 shorts (256 KB)
  short* Woutb = (short*)(ws + 92160);   // 2048 shorts (4 KB)
  float* ostp  = ws + 93184;     // 2560
  float* sc    = ws + 95744;     // 320
  float* sh    = ws + 96064;     // 320

  float* outy = (float*)d_out;
  float* hout = outy + (size_t)BB * TT * 5;
  float* cout = hout + (size_t)BB * 128;

  hipFuncSetAttribute((const void*)lstm_kernel,
                      hipFuncAttributeMaxDynamicSharedMemorySize, LSTM_LDS_BYTES);

  prep_kernel <<<67, 256, 0, stream>>>(Wih, Whh, bih, bhh, Wout, Wcb, Woutb, bcg);
  stats_kernel<<<64, 256, 0, stream>>>(xin, stats);
  coef_kernel <<<1, 128, 0, stream>>>(stats, Wemb, bemb, ing, inb, eg, eb, A0, A1, Ct);
  lstm_kernel <<<256, 1024, LSTM_LDS_BYTES, stream>>>(xin, A0, A1, Ct, Wcb, bcg, Woutb, bout,
                                                      outy, hout, cout);
  ostats_kernel<<<256, 256, 0, stream>>>(outy, ostp);
  ofin_kernel <<<1, 320, 0, stream>>>(ostp, og, ob, sc, sh);
  onorm_kernel<<<2048, 256, 0, stream>>>(outy, sc, sh);
}

// Round 9
// 304.820 us; speedup vs baseline: 2.6327x; 2.6327x over previous
//
#include <hip/hip_runtime.h>
#include <hip/hip_bf16.h>

#define BB 8192
#define TT 64
#define L2E 1.44269504088896f

typedef __attribute__((ext_vector_type(8))) short bf16x8;
typedef __attribute__((ext_vector_type(4))) float f32x4;

__device__ __forceinline__ float exp2g(float x) { return __builtin_amdgcn_exp2f(x); }
__device__ __forceinline__ float rcpg(float x)  { return __builtin_amdgcn_rcpf(x); }
__device__ __forceinline__ short f2bf_s(float x) {
  __hip_bfloat16 b = __float2bfloat16(x);
  return *reinterpret_cast<short*>(&b);
}
// acts[row][k], k in [0,512): e_buf0, e_buf1, h_buf0, h_buf1. 16B-granule XOR swizzle.
__device__ __forceinline__ int aidx(int row, int k) {
  return row * 512 + ((((k >> 3) ^ (row & 7))) << 3) + (k & 7);
}
__device__ __forceinline__ bf16x8 ldg(const short* acts, int row, int kg) {
  return *(const bf16x8*)&acts[row * 512 + ((kg ^ (row & 7)) << 3)];
}

// ---- 1. weights -> bf16 MFMA B-fragment order, exp2-prescaled; bc = (b_ih+b_hh)*scale ----
// Wcb frag f = kt*32+nt: lane l elem e = scale(gate) * Wc[kt*32+(l>>4)*8+e][nt*16+(l&15)]
__global__ void prep_kernel(const float* __restrict__ Wih, const float* __restrict__ Whh,
                            const float* __restrict__ bih, const float* __restrict__ bhh,
                            const float* __restrict__ Wout,
                            short* __restrict__ Wcb, short* __restrict__ Woutb,
                            float* __restrict__ bc) {
  int idx = blockIdx.x * 256 + threadIdx.x;   // 17152 total
  if (idx < 16384) {
    int l = idx & 63, f = idx >> 6;
    int kt = f >> 5, nt = f & 31;
    int k0 = kt * 32 + ((l >> 4) << 3);
    int col = nt * 16 + (l & 15);
    int gate = col >> 7;
    float s = (gate == 2) ? (2.f * L2E) : (-L2E);
    const float* src = (k0 < 128) ? (Wih + col * 128 + k0) : (Whh + col * 128 + (k0 - 128));
    bf16x8 v;
    #pragma unroll
    for (int e = 0; e < 8; e++) v[e] = f2bf_s(src[e] * s);
    *(bf16x8*)(Wcb + (size_t)idx * 8) = v;
  } else if (idx < 16640) {
    int i2 = idx - 16384;
    int l = i2 & 63, f = i2 >> 6;              // f = kyt
    int k0 = f * 32 + ((l >> 4) << 3);
    int col = l & 15;
    bf16x8 v;
    #pragma unroll
    for (int e = 0; e < 8; e++)
      v[e] = (col < 5) ? f2bf_s(Wout[col * 128 + k0 + e]) : (short)0;
    *(bf16x8*)(Woutb + (size_t)i2 * 8) = v;
  } else {
    int i3 = idx - 16640;
    int gate = i3 >> 7;
    float s = (gate == 2) ? (2.f * L2E) : (-L2E);
    bc[i3] = (bih[i3] + bhh[i3]) * s;
  }
}

// ---- 2. per-t raw input moments over batch ----
__global__ void stats_kernel(const float* __restrict__ x, float* __restrict__ stats) {
  int t = blockIdx.x, tid = threadIdx.x;
  float s0=0, s1=0, s2=0, s3=0, s4=0;
  for (int b = tid; b < BB; b += 256) {
    const float* p = x + ((size_t)b * TT + t) * 2;
    float x0 = p[0], x1 = p[1];
    s0 += x0; s1 += x1; s2 += x0*x0; s3 += x0*x1; s4 += x1*x1;
  }
  __shared__ float red[4][5];
  int lane = tid & 63, w = tid >> 6;
  #pragma unroll
  for (int off = 32; off > 0; off >>= 1) {
    s0 += __shfl_down(s0, off); s1 += __shfl_down(s1, off);
    s2 += __shfl_down(s2, off); s3 += __shfl_down(s3, off); s4 += __shfl_down(s4, off);
  }
  if (lane == 0) { red[w][0]=s0; red[w][1]=s1; red[w][2]=s2; red[w][3]=s3; red[w][4]=s4; }
  __syncthreads();
  if (tid < 5) stats[t*5 + tid] = red[0][tid] + red[1][tid] + red[2][tid] + red[3][tid];
}

// ---- 3. fold input-BN + embed Linear + per-step embed-BN into A0/A1/C ----
__global__ void coef_kernel(const float* __restrict__ stats,
                            const float* __restrict__ Wemb, const float* __restrict__ bemb,
                            const float* __restrict__ ing, const float* __restrict__ inb,
                            const float* __restrict__ eg, const float* __restrict__ eb,
                            float* __restrict__ A0, float* __restrict__ A1, float* __restrict__ Ct) {
  __shared__ float st[64][5];
  __shared__ float glob[4];
  int tid = threadIdx.x;  // 128
  for (int i = tid; i < 320; i += 128) st[i / 5][i % 5] = stats[i];
  __syncthreads();
  if (tid == 0) {
    float S0=0, S1=0, S00=0, S11=0;
    for (int t = 0; t < 64; t++) { S0+=st[t][0]; S1+=st[t][1]; S00+=st[t][2]; S11+=st[t][4]; }
    float inv_n = 1.f / (float)(BB * TT);
    float M0 = S0*inv_n, M1 = S1*inv_n;
    float V0 = S00*inv_n - M0*M0, V1 = S11*inv_n - M1*M1;
    float P0 = rsqrtf(V0 + 1e-5f) * ing[0];
    float P1 = rsqrtf(V1 + 1e-5f) * ing[1];
    glob[0]=P0; glob[1]=P1; glob[2]=inb[0]-M0*P0; glob[3]=inb[1]-M1*P1;
  }
  __syncthreads();
  float P0=glob[0], P1=glob[1], Q0=glob[2], Q1=glob[3];
  int j = tid;
  float w0 = Wemb[j*2], w1 = Wemb[j*2+1];
  float a0 = P0*w0, a1 = P1*w1;
  float cj = Q0*w0 + Q1*w1 + bemb[j];
  float gam = eg[j], bet = eb[j];
  float invB = 1.f / (float)BB;
  for (int t = 0; t < 64; t++) {
    float m0 = st[t][0]*invB, m1 = st[t][1]*invB;
    float v00 = st[t][2]*invB - m0*m0;
    float v01 = st[t][3]*invB - m0*m1;
    float v11 = st[t][4]*invB - m1*m1;
    float mean = a0*m0 + a1*m1 + cj;
    float var  = a0*a0*v00 + 2.f*a0*a1*v01 + a1*a1*v11;
    float G = rsqrtf(var + 1e-5f) * gam;
    A0[t*128 + j] = G * a0;
    A1[t*128 + j] = G * a1;
    Ct[t*128 + j] = G * cj + (bet - mean * G);
  }
}

// write e(t) for row er, granule cg, into e-buffer (t&1)
__device__ __forceinline__ void write_e(short* acts_s,
                                        const float* __restrict__ A0, const float* __restrict__ A1,
                                        const float* __restrict__ Ct,
                                        int t, int er, int cg, const float* __restrict__ xs) {
  const float* a0p = A0 + t*128 + cg*8;
  const float* a1p = A1 + t*128 + cg*8;
  const float* ccp = Ct + t*128 + cg*8;
  const float4 a0a = *(const float4*)a0p, a0b = *(const float4*)(a0p + 4);
  const float4 a1a = *(const float4*)a1p, a1b = *(const float4*)(a1p + 4);
  const float4 cta = *(const float4*)ccp, ctb = *(const float4*)(ccp + 4);
  float x0 = xs[er * 128 + t * 2], x1 = xs[er * 128 + t * 2 + 1];
  bf16x8 v;
  v[0] = f2bf_s(fmaxf(fmaf(a0a.x, x0, fmaf(a1a.x, x1, cta.x)), 0.f));
  v[1] = f2bf_s(fmaxf(fmaf(a0a.y, x0, fmaf(a1a.y, x1, cta.y)), 0.f));
  v[2] = f2bf_s(fmaxf(fmaf(a0a.z, x0, fmaf(a1a.z, x1, cta.z)), 0.f));
  v[3] = f2bf_s(fmaxf(fmaf(a0a.w, x0, fmaf(a1a.w, x1, cta.w)), 0.f));
  v[4] = f2bf_s(fmaxf(fmaf(a0b.x, x0, fmaf(a1b.x, x1, ctb.x)), 0.f));
  v[5] = f2bf_s(fmaxf(fmaf(a0b.y, x0, fmaf(a1b.y, x1, ctb.y)), 0.f));
  v[6] = f2bf_s(fmaxf(fmaf(a0b.z, x0, fmaf(a1b.z, x1, ctb.z)), 0.f));
  v[7] = f2bf_s(fmaxf(fmaf(a0b.w, x0, fmaf(a1b.w, x1, ctb.w)), 0.f));
  int gk = (t & 1) * 16 + cg;
  *(bf16x8*)&acts_s[er * 512 + ((gk ^ (er & 7)) << 3)] = v;
}

// ---- 4. MFMA recurrence, e-part/y pipelined against elementwise ----
// 256 blocks x 32 rows, 8 waves, weights resident (128 VGPR), 2 waves/SIMD
__launch_bounds__(512, 1)
__global__ void lstm_kernel(const float* __restrict__ x,
                            const float* __restrict__ A0, const float* __restrict__ A1,
                            const float* __restrict__ Ctab,
                            const short* __restrict__ Wcb, const float* __restrict__ bc,
                            const short* __restrict__ Woutb, const float* __restrict__ bout,
                            float* __restrict__ outy, float* __restrict__ hout,
                            float* __restrict__ cout) {
  __shared__ __align__(16) short acts_s[32 * 512];  // e0 e1 h0 h1, swizzled granules
  __shared__ __align__(16) float xs[32 * 128];

  const int tid  = threadIdx.x;
  const int lane = tid & 63;
  const int w    = tid >> 6;        // wave 0..7 -> col slice w*16 of each gate
  const int row0 = blockIdx.x * 32;
  const int cl   = lane & 15;
  const int lq   = lane >> 4;
  const int er   = tid >> 4;        // e-writer row 0..31
  const int cg   = tid & 15;        // e-writer granule

  // preload x for this block's 32 rows
  {
    const float4* src = (const float4*)(x + (size_t)row0 * 128);
    float4* dst = (float4*)xs;
    dst[tid]       = src[tid];
    dst[tid + 512] = src[tid + 512];
  }

  float bgs[4];
  #pragma unroll
  for (int g = 0; g < 4; g++) bgs[g] = bc[g * 128 + w * 16 + cl];
  const float bov = (cl < 5) ? bout[cl] : 0.f;

  // gate weights resident in VGPRs: 32 fragments = 128 VGPRs
  bf16x8 wreg[8][4];
  {
    const bf16x8* wptr = (const bf16x8*)Wcb;
    #pragma unroll
    for (int kt = 0; kt < 8; kt++)
      #pragma unroll
      for (int g = 0; g < 4; g++)
        wreg[kt][g] = wptr[(size_t)(kt * 32 + g * 8 + w) * 64 + lane];
  }

  __syncthreads();  // xs ready

  // prologue: e(0) -> ebuf0; h(-1)=0 -> hbuf1
  write_e(acts_s, A0, A1, Ctab, 0, er, cg, xs);
  {
    bf16x8 z = (bf16x8)0;
    int gk = 48 + cg;               // h-buf 1
    *(bf16x8*)&acts_s[er * 512 + ((gk ^ (er & 7)) << 3)] = z;
  }
  __syncthreads();

  // prologue: acc = bias + e-part(0); write e(1)
  f32x4 acc[4][2];
  #pragma unroll
  for (int g = 0; g < 4; g++) {
    acc[g][0] = (f32x4){bgs[g], bgs[g], bgs[g], bgs[g]};
    acc[g][1] = acc[g][0];
  }
  #pragma unroll
  for (int kt = 0; kt < 4; kt++) {
    bf16x8 a0 = ldg(acts_s, cl, kt * 4 + lq);
    bf16x8 a1 = ldg(acts_s, 16 + cl, kt * 4 + lq);
    #pragma unroll
    for (int g = 0; g < 4; g++) {
      acc[g][0] = __builtin_amdgcn_mfma_f32_16x16x32_bf16(a0, wreg[kt][g], acc[g][0], 0, 0, 0);
      acc[g][1] = __builtin_amdgcn_mfma_f32_16x16x32_bf16(a1, wreg[kt][g], acc[g][1], 0, 0, 0);
    }
  }
  write_e(acts_s, A0, A1, Ctab, 1, er, cg, xs);
  __syncthreads();

  f32x4 cstate[2] = {{0.f,0.f,0.f,0.f},{0.f,0.f,0.f,0.f}};

  #pragma unroll 1
  for (int t = 0; t < TT; t++) {
    const int hb_prev = (t + 1) & 1;   // h(t-1)
    const int hb_cur  = t & 1;         // h(t)
    const int eb_next = (t + 1) & 1;   // e(t+1)

    // ---- h-part MFMA: acc += h(t-1) @ Whh ----
    #pragma unroll
    for (int kt = 0; kt < 4; kt++) {
      int kgh = 32 + hb_prev * 16 + kt * 4 + lq;
      bf16x8 a0 = ldg(acts_s, cl, kgh);
      bf16x8 a1 = ldg(acts_s, 16 + cl, kgh);
      #pragma unroll
      for (int g = 0; g < 4; g++) {
        acc[g][0] = __builtin_amdgcn_mfma_f32_16x16x32_bf16(a0, wreg[4 + kt][g], acc[g][0], 0, 0, 0);
        acc[g][1] = __builtin_amdgcn_mfma_f32_16x16x32_bf16(a1, wreg[4 + kt][g], acc[g][1], 0, 0, 0);
      }
    }

    // ---- independent work fills the acc-latency window ----
    if (t < TT - 2) write_e(acts_s, A0, A1, Ctab, t + 2, er, cg, xs);  // -> ebuf[t&1]
    if ((w & 3) == 0 && t > 0) {       // y(t-1): waves 0,4; reads hbuf[hb_prev]
      int mty = w >> 2;
      f32x4 ya = (f32x4){0.f, 0.f, 0.f, 0.f};
      #pragma unroll
      for (int kyt = 0; kyt < 4; kyt++) {
        bf16x8 wo = *(const bf16x8*)(Woutb + (size_t)(kyt * 64 + lane) * 8);
        bf16x8 ah = ldg(acts_s, mty * 16 + cl, 32 + hb_prev * 16 + kyt * 4 + lq);
        ya = __builtin_amdgcn_mfma_f32_16x16x32_bf16(ah, wo, ya, 0, 0, 0);
      }
      if (cl < 5) {
        #pragma unroll
        for (int q = 0; q < 4; q++) {
          int brow = row0 + mty * 16 + lq * 4 + q;
          outy[((size_t)brow * TT + (t - 1)) * 5 + cl] = ya[q] + bov;
        }
      }
    }

    // ---- per M-tile: elementwise consumes acc, then refill with e-part(t+1) ----
    #pragma unroll
    for (int mt = 0; mt < 2; mt++) {
      #pragma unroll
      for (int q = 0; q < 4; q++) {
        float Ei = exp2g(acc[0][mt][q]);          // e^{-i}
        float Ef = exp2g(acc[1][mt][q]);          // e^{-f}
        float Eg = exp2g(acc[2][mt][q]);          // e^{2g}
        float Eo = exp2g(acc[3][mt][q]);          // e^{-o}
        float ig = (Eg - 1.f) * rcpg((1.f + Ei) * (1.f + Eg));
        float fv = rcpg(1.f + Ef);
        float cn = fmaf(fv, cstate[mt][q], ig);
        cstate[mt][q] = cn;
        float Ec = exp2g(cn * (2.f * L2E));
        float hn = (Ec - 1.f) * rcpg((1.f + Eo) * (1.f + Ec));
        int row = mt * 16 + lq * 4 + q;
        int k   = 256 + hb_cur * 128 + w * 16 + cl;
        acts_s[aidx(row, k)] = f2bf_s(hn);
        if (t == TT - 1) {
          hout[(size_t)(row0 + row) * 128 + w * 16 + cl] = hn;
          cout[(size_t)(row0 + row) * 128 + w * 16 + cl] = cn;
        }
      }
      if (t < TT - 1) {                // refill acc[.][mt] = bias + e(t+1)-part
        #pragma unroll
        for (int g = 0; g < 4; g++)
          acc[g][mt] = (f32x4){bgs[g], bgs[g], bgs[g], bgs[g]};
        #pragma unroll
        for (int kt = 0; kt < 4; kt++) {
          bf16x8 a = ldg(acts_s, mt * 16 + cl, eb_next * 16 + kt * 4 + lq);
          #pragma unroll
          for (int g = 0; g < 4; g++)
            acc[g][mt] = __builtin_amdgcn_mfma_f32_16x16x32_bf16(a, wreg[kt][g], acc[g][mt], 0, 0, 0);
        }
      }
    }

    __syncthreads();  // h(t), e(t+2) visible; hbuf[hb_prev]/ebuf reads done
  }

  // epilogue: y(63)
  if ((w & 3) == 0) {
    int mty = w >> 2;
    f32x4 ya = (f32x4){0.f, 0.f, 0.f, 0.f};
    #pragma unroll
    for (int kyt = 0; kyt < 4; kyt++) {
      bf16x8 wo = *(const bf16x8*)(Woutb + (size_t)(kyt * 64 + lane) * 8);
      bf16x8 ah = ldg(acts_s, mty * 16 + cl, 32 + ((TT - 1) & 1) * 16 + kyt * 4 + lq);
      ya = __builtin_amdgcn_mfma_f32_16x16x32_bf16(ah, wo, ya, 0, 0, 0);
    }
    if (cl < 5) {
      #pragma unroll
      for (int q = 0; q < 4; q++) {
        int brow = row0 + mty * 16 + lq * 4 + q;
        outy[((size_t)brow * TT + (TT - 1)) * 5 + cl] = ya[q] + bov;
      }
    }
  }
}

// ---- 5. per-(t,k) output BN partial stats (256 blocks = full chip) ----
__global__ void ostats_kernel(const float* __restrict__ outy, float* __restrict__ ostp) {
  int t = blockIdx.x >> 2, part = blockIdx.x & 3;
  int tid = threadIdx.x;
  float s[5] = {0,0,0,0,0}, s2[5] = {0,0,0,0,0};
  int b0 = part * 2048;
  for (int b = b0 + tid; b < b0 + 2048; b += 256) {
    const float* p = outy + ((size_t)b * TT + t) * 5;
    #pragma unroll
    for (int k = 0; k < 5; k++) { float v = p[k]; s[k] += v; s2[k] += v*v; }
  }
  __shared__ float red[4][10];
  int lane = tid & 63, w = tid >> 6;
  #pragma unroll
  for (int off = 32; off > 0; off >>= 1) {
    #pragma unroll
    for (int k = 0; k < 5; k++) {
      s[k]  += __shfl_down(s[k], off);
      s2[k] += __shfl_down(s2[k], off);
    }
  }
  if (lane == 0) {
    #pragma unroll
    for (int k = 0; k < 5; k++) { red[w][k] = s[k]; red[w][5+k] = s2[k]; }
  }
  __syncthreads();
  if (tid < 10) ostp[blockIdx.x * 10 + tid] = red[0][tid]+red[1][tid]+red[2][tid]+red[3][tid];
}

// ---- 5b. finalize: per-(t,k) scale/shift ----
__global__ void ofin_kernel(const float* __restrict__ ostp,
                            const float* __restrict__ og, const float* __restrict__ ob,
                            float* __restrict__ sc, float* __restrict__ sh) {
  int i = threadIdx.x;               // 320
  if (i >= 320) return;
  int t = i / 5, k = i - t * 5;
  const float invB = 1.f / (float)BB;
  float m  = (ostp[(t*4+0)*10+k]   + ostp[(t*4+1)*10+k]   + ostp[(t*4+2)*10+k]   + ostp[(t*4+3)*10+k]) * invB;
  float s2 = (ostp[(t*4+0)*10+5+k] + ostp[(t*4+1)*10+5+k] + ostp[(t*4+2)*10+5+k] + ostp[(t*4+3)*10+5+k]) * invB;
  float v = s2 - m * m;
  float scale = rsqrtf(v + 1e-5f) * og[k];
  sc[i] = scale;
  sh[i] = ob[k] - m * scale;
}

// ---- 6. normalize outs in place ----
__global__ void onorm_kernel(float* __restrict__ outy, const float* __restrict__ sc,
                             const float* __restrict__ sh) {
  const int N = BB * TT * 5;
  for (int i = blockIdx.x * 256 + threadIdx.x; i < N; i += gridDim.x * 256) {
    int j = i % 320;
    outy[i] = fmaf(outy[i], sc[j], sh[j]);
  }
}

extern "C" void kernel_launch(void* const* d_in, const int* in_sizes, int n_in,
                              void* d_out, int out_size, void* d_ws, size_t ws_size,
                              hipStream_t stream) {
  const float* xin  = (const float*)d_in[0];
  const float* ing  = (const float*)d_in[1];
  const float* inb  = (const float*)d_in[2];
  const float* Wemb = (const float*)d_in[3];
  const float* bemb = (const float*)d_in[4];
  const float* eg   = (const float*)d_in[5];
  const float* eb   = (const float*)d_in[6];
  const float* Wih  = (const float*)d_in[7];
  const float* Whh  = (const float*)d_in[8];
  const float* bih  = (const float*)d_in[9];
  const float* bhh  = (const float*)d_in[10];
  const float* Wout = (const float*)d_in[11];
  const float* bout = (const float*)d_in[12];
  const float* og   = (const float*)d_in[13];
  const float* ob   = (const float*)d_in[14];

  float* ws    = (float*)d_ws;
  float* stats = ws;             // 320
  float* A0    = ws + 1024;      // 8192
  float* A1    = ws + 9216;      // 8192
  float* Ct    = ws + 17408;     // 8192
  float* bc    = ws + 25600;     // 512
  short* Wcb   = (short*)(ws + 26624);   // 131072 shorts (256 KB)
  short* Woutb = (short*)(ws + 92160);   // 2048 shorts (4 KB)
  float* ostp  = ws + 93184;     // 2560
  float* sc    = ws + 95744;     // 320
  float* sh    = ws + 96064;     // 320

  float* outy = (float*)d_out;
  float* hout = outy + (size_t)BB * TT * 5;
  float* cout = hout + (size_t)BB * 128;

  prep_kernel <<<67, 256, 0, stream>>>(Wih, Whh, bih, bhh, Wout, Wcb, Woutb, bc);
  stats_kernel<<<64, 256, 0, stream>>>(xin, stats);
  coef_kernel <<<1, 128, 0, stream>>>(stats, Wemb, bemb, ing, inb, eg, eb, A0, A1, Ct);
  lstm_kernel <<<256, 512, 0, stream>>>(xin, A0, A1, Ct, Wcb, bc, Woutb, bout,
                                        outy, hout, cout);
  ostats_kernel<<<256, 256, 0, stream>>>(outy, ostp);
  ofin_kernel <<<1, 320, 0, stream>>>(ostp, og, ob, sc, sh);
  onorm_kernel<<<2048, 256, 0, stream>>>(outy, sc, sh);
}